// Round 8
// baseline (18528.076 us; speedup 1.0000x reference)
//
#include <hip/hip_runtime.h>

typedef __attribute__((ext_vector_type(4))) float f32x4;
typedef __attribute__((ext_vector_type(8))) short short8;
typedef __attribute__((ext_vector_type(4))) short short4v;

// Padded LDS layout: logical index I -> word I + (I>>4); one pad word per 16.
// Lane addresses are 17*t + const => exactly 2 lanes/bank => conflict-free.
#define PADW(I) ((I) + ((I) >> 4))
// Affine form: PADW(16*t + z) == 17*t + WOFF(z), WOFF(z) compile-time.
#define WOFF(z) ((z) + ((z) >> 4))

constexpr int LROW = 4096;
constexpr int KW   = 64;
constexpr int HALO = 32;                      // pad_lo=31, pad_hi=32
constexpr int NLOG = LROW + 2 * HALO;         // 4160
constexpr int XS_SIZE = PADW(NLOG - 1) + 1;   // 4419 words

__device__ __forceinline__ float shrinkf(float c, float theta) {
  float a = fabsf(c) - theta;
  return (a > 0.0f) ? copysignf(a, c) : 0.0f;
}

// wave-uniform float -> SGPR (bit-exact; readfirstlane is int-typed!)
__device__ __forceinline__ float rfl_f32(float v) {
  return __int_as_float(__builtin_amdgcn_readfirstlane(__float_as_int(v)));
}

// conv over this thread's 16 consecutive outputs with rolling-window reuse.
// xw = xs + 17*t (affine base; LDS reads use immediate offsets).
// kn taps are SGPR-resident (wave-uniform) so the inner loop is a pure
// v_fmac_f32 vdst, s_kn, v_wv stream.
template <typename KN>
__device__ __forceinline__ void conv_row(const float* __restrict__ xw,
                                         const KN& kn, float acc[16]) {
#pragma unroll
  for (int e = 0; e < 16; ++e) acc[e] = 0.0f;
#pragma unroll
  for (int m = 0; m < 79; ++m) {
    float wv = xw[WOFF(1 + m)];
    const int jlo = (m - 15 > 0) ? (m - 15) : 0;
    const int jhi = (m < 63) ? m : 63;
#pragma unroll
    for (int j = jlo; j <= jhi; ++j) {
      acc[m - j] = fmaf(kn(j), wv, acc[m - j]);
    }
  }
}

__global__ __launch_bounds__(256) void ista_kernel(
    const float* __restrict__ y, const float* __restrict__ pulse,
    float* __restrict__ xout) {
  __shared__ float xs[XS_SIZE];
  __shared__ float pl[KW];
  __shared__ float knl[KW];

  const int t = threadIdx.x;
  const int row = blockIdx.x;

  if (t < KW) pl[t] = pulse[t];
  if (t < HALO) {                       // zero halos (stay zero forever)
    xs[PADW(t)] = 0.0f;
    xs[PADW(NLOG - HALO + t)] = 0.0f;
  }
  // stage y row into xs (coalesced float4 loads)
  const float* yrow = y + (size_t)row * LROW;
#pragma unroll
  for (int q = 0; q < 4; ++q) {
    int i4 = q * 256 + t;
    float4 v = ((const float4*)yrow)[i4];
    xs[PADW(HALO + 4 * i4 + 0)] = v.x;
    xs[PADW(HALO + 4 * i4 + 1)] = v.y;
    xs[PADW(HALO + 4 * i4 + 2)] = v.z;
    xs[PADW(HALO + 4 * i4 + 3)] = v.w;
  }
  __syncthreads();

  // L_const = sum pulse^2 (redundant per-thread, broadcast LDS reads, once)
  float Lc = 0.0f;
#pragma unroll
  for (int j = 0; j < KW; ++j) Lc += pl[j] * pl[j];
  const float theta = 0.1f / Lc;
  if (t < KW) knl[t] = pl[KW - 1 - t] / Lc;  // reversed pulse, pre-divided by L
  __syncthreads();

  // hoist the 64 taps into wave-uniform scalars (SGPRs). Each k<i> is an
  // independent scalar SSA value; all uses below have compile-time indices.
#define KDECL(i) const float k##i = rfl_f32(knl[i]);
  KDECL(0)  KDECL(1)  KDECL(2)  KDECL(3)  KDECL(4)  KDECL(5)  KDECL(6)  KDECL(7)
  KDECL(8)  KDECL(9)  KDECL(10) KDECL(11) KDECL(12) KDECL(13) KDECL(14) KDECL(15)
  KDECL(16) KDECL(17) KDECL(18) KDECL(19) KDECL(20) KDECL(21) KDECL(22) KDECL(23)
  KDECL(24) KDECL(25) KDECL(26) KDECL(27) KDECL(28) KDECL(29) KDECL(30) KDECL(31)
  KDECL(32) KDECL(33) KDECL(34) KDECL(35) KDECL(36) KDECL(37) KDECL(38) KDECL(39)
  KDECL(40) KDECL(41) KDECL(42) KDECL(43) KDECL(44) KDECL(45) KDECL(46) KDECL(47)
  KDECL(48) KDECL(49) KDECL(50) KDECL(51) KDECL(52) KDECL(53) KDECL(54) KDECL(55)
  KDECL(56) KDECL(57) KDECL(58) KDECL(59) KDECL(60) KDECL(61) KDECL(62) KDECL(63)
#undef KDECL
  auto kn = [&](int j) -> float {
    switch (j) {
#define KCASE(i) case i: return k##i;
      KCASE(0)  KCASE(1)  KCASE(2)  KCASE(3)  KCASE(4)  KCASE(5)  KCASE(6)  KCASE(7)
      KCASE(8)  KCASE(9)  KCASE(10) KCASE(11) KCASE(12) KCASE(13) KCASE(14) KCASE(15)
      KCASE(16) KCASE(17) KCASE(18) KCASE(19) KCASE(20) KCASE(21) KCASE(22) KCASE(23)
      KCASE(24) KCASE(25) KCASE(26) KCASE(27) KCASE(28) KCASE(29) KCASE(30) KCASE(31)
      KCASE(32) KCASE(33) KCASE(34) KCASE(35) KCASE(36) KCASE(37) KCASE(38) KCASE(39)
      KCASE(40) KCASE(41) KCASE(42) KCASE(43) KCASE(44) KCASE(45) KCASE(46) KCASE(47)
      KCASE(48) KCASE(49) KCASE(50) KCASE(51) KCASE(52) KCASE(53) KCASE(54) KCASE(55)
      KCASE(56) KCASE(57) KCASE(58) KCASE(59) KCASE(60) KCASE(61) KCASE(62) KCASE(63)
#undef KCASE
    }
    return 0.0f;
  };

  float* xw = xs + 17 * t;              // affine base for this thread

  // B_term = conv(y)/L (taps pre-divided); kept in registers for all iters
  float bt[16];
  conv_row(xw, kn, bt);
  __syncthreads();

  // iteration 1: x1 = shrink(B_term)  (x0 = 0 => conv term vanishes)
#pragma unroll
  for (int e = 0; e < 16; ++e)
    xw[WOFF(32 + e)] = shrinkf(bt[e], theta);
  __syncthreads();

  // remaining 19 ISTA iterations entirely in LDS/registers
  for (int it = 0; it < 19; ++it) {
    float acc[16];
    conv_row(xw, kn, acc);
    float xn[16];
#pragma unroll
    for (int e = 0; e < 16; ++e) {
      float xcur = xw[WOFF(32 + e)];
      xn[e] = shrinkf(bt[e] + xcur - acc[e], theta);
    }
    __syncthreads();                     // all reads of old x done
#pragma unroll
    for (int e = 0; e < 16; ++e) xw[WOFF(32 + e)] = xn[e];
    __syncthreads();                     // new x visible to all
  }

  // write x out, coalesced float4
  float* xr = xout + (size_t)row * LROW;
#pragma unroll
  for (int q = 0; q < 4; ++q) {
    int i4 = q * 256 + t;
    float4 v;
    v.x = xs[PADW(HALO + 4 * i4 + 0)];
    v.y = xs[PADW(HALO + 4 * i4 + 1)];
    v.z = xs[PADW(HALO + 4 * i4 + 2)];
    v.w = xs[PADW(HALO + 4 * i4 + 3)];
    ((float4*)xr)[i4] = v;
  }
}

// ---------------- MLP via bf16 MFMA (validated in R2) ----------------
__device__ __forceinline__ unsigned short f2bf(float f) {
  unsigned u = __float_as_uint(f);
  u += 0x7fffu + ((u >> 16) & 1u);      // RNE
  return (unsigned short)(u >> 16);
}

__global__ __launch_bounds__(256) void cast_w1(const float* __restrict__ W1,
                                               unsigned short* __restrict__ W1p) {
  const int kq = blockIdx.x;
  const int c  = threadIdx.x;
  short8 v;
#pragma unroll
  for (int j = 0; j < 8; ++j)
    v[j] = (short)f2bf(W1[(size_t)(kq * 8 + j) * 256 + c]);
  *(short8*)(W1p + ((size_t)kq * 256 + c) * 8) = v;
}

__global__ __launch_bounds__(256) void mlp_mfma(
    const float* __restrict__ x, const unsigned short* __restrict__ W1p,
    const float* __restrict__ b1, const float* __restrict__ W2,
    const float* __restrict__ b2, float* __restrict__ out1) {
  __shared__ short Ap[16 * 8 * 8];
  __shared__ short Bp[8 * 256 * 8];
  __shared__ float pr[4][16];

  const int t = threadIdx.x;
  const int w = t >> 6;
  const int l = t & 63;
  const int lrow = l & 15;
  const int lk   = l >> 4;
  const int row0 = blockIdx.x * 16;

  f32x4 acc[4];
#pragma unroll
  for (int n = 0; n < 4; ++n) acc[n] = (f32x4)0.0f;

  for (int kt = 0; kt < 64; ++kt) {
    __syncthreads();
    {
      const int r  = t >> 4;
      const int k4 = t & 15;
      const float4 v = *(const float4*)(x + (size_t)(row0 + r) * LROW + kt * 64 + k4 * 4);
      short4v a;
      a.x = (short)f2bf(v.x); a.y = (short)f2bf(v.y);
      a.z = (short)f2bf(v.z); a.w = (short)f2bf(v.w);
      const int kq = k4 >> 1, h = k4 & 1;
      *(short4v*)((char*)Ap + ((r * 8 + (kq ^ (r & 7))) * 16 + h * 8)) = a;
    }
    {
      const short8* src = (const short8*)(W1p + (size_t)kt * (8 * 256 * 8));
      short8* dst = (short8*)Bp;
#pragma unroll
      for (int i = 0; i < 8; ++i) dst[t + 256 * i] = src[t + 256 * i];
    }
    __syncthreads();
#pragma unroll
    for (int kf = 0; kf < 2; ++kf) {
      const int kq = kf * 4 + lk;
      short8 af = *(short8*)((char*)Ap + (lrow * 8 + (kq ^ (lrow & 7))) * 16);
#pragma unroll
      for (int n = 0; n < 4; ++n) {
        short8 bf = *(short8*)((char*)Bp + (kq * 256 + w * 64 + n * 16 + lrow) * 16);
        acc[n] = __builtin_amdgcn_mfma_f32_16x16x32_bf16(af, bf, acc[n], 0, 0, 0);
      }
    }
  }

  float s[4] = {0.0f, 0.0f, 0.0f, 0.0f};
#pragma unroll
  for (int n = 0; n < 4; ++n) {
    const int c = w * 64 + n * 16 + lrow;
    const float b1v = b1[c];
    const float w2v = W2[c];
#pragma unroll
    for (int i = 0; i < 4; ++i) {
      float f = acc[n][i] + b1v;
      f = fmaxf(f, 0.0f);
      s[i] = fmaf(f, w2v, s[i]);
    }
  }
#pragma unroll
  for (int off = 1; off < 16; off <<= 1) {
#pragma unroll
    for (int i = 0; i < 4; ++i) s[i] += __shfl_xor(s[i], off, 64);
  }
  if (lrow == 0) {
#pragma unroll
    for (int i = 0; i < 4; ++i) pr[w][lk * 4 + i] = s[i];
  }
  __syncthreads();
  if (t < 16) {
    out1[row0 + t] =
        (pr[0][t] + pr[1][t] + pr[2][t] + pr[3][t] + b2[0]) * (float)LROW;
  }
}

extern "C" void kernel_launch(void* const* d_in, const int* in_sizes, int n_in,
                              void* d_out, int out_size, void* d_ws, size_t ws_size,
                              hipStream_t stream) {
  const float* y     = (const float*)d_in[0];
  const float* pulse = (const float*)d_in[1];
  const float* W1    = (const float*)d_in[2];
  const float* b1    = (const float*)d_in[3];
  const float* W2    = (const float*)d_in[4];
  const float* b2    = (const float*)d_in[5];

  float* xout = (float*)d_out;
  float* out1 = xout + (size_t)LROW * LROW;
  unsigned short* W1p = (unsigned short*)d_ws;

  cast_w1<<<512, 256, 0, stream>>>(W1, W1p);
  ista_kernel<<<LROW, 256, 0, stream>>>(y, pulse, xout);
  mlp_mfma<<<LROW / 16, 256, 0, stream>>>(xout, W1p, b1, W2, b2, out1);
}

// Round 9
// 398.941 us; speedup vs baseline: 46.4431x; 46.4431x over previous
//
#include <hip/hip_runtime.h>

typedef __attribute__((ext_vector_type(4))) float f32x4;
typedef __attribute__((ext_vector_type(8))) short short8;
typedef __attribute__((ext_vector_type(4))) short short4v;

#define PADW(I) ((I) + ((I) >> 4))
#define WOFF(z) ((z) + ((z) >> 4))

constexpr int LROW = 4096;
constexpr int KW   = 64;
constexpr int HALO = 32;
constexpr int NLOG = LROW + 2 * HALO;
constexpr int XS_SIZE = PADW(NLOG - 1) + 1;   // 4419 f32 words

// bf16x3 LDS geometry: per buffer three u16 arrays (h, m*2^8, l*2^16),
// 4176 entries each (x index i at n=i+32; halos stay zero).
constexpr int AS    = 8384;
constexpr int SLOT  = 3 * AS;      // 25152 B
constexpr int POOLB = 2 * SLOT;    // 50304 B
static_assert(XS_SIZE * 4 <= SLOT, "y f32 stage fits in buf1 region");

__device__ __forceinline__ float bfh2f(unsigned short h) {
  return __uint_as_float(((unsigned)h) << 16);
}
__device__ __forceinline__ unsigned short btrunc(float x) {
  return (unsigned short)(__float_as_uint(x) >> 16);
}
// exact scaled split: x = h + m*2^-8 + l*2^-16 + O(2^-24 x); all steps exact.
__device__ __forceinline__ void split3s(float x, unsigned short& h,
                                        unsigned short& m, unsigned short& l) {
  h = btrunc(x);
  float r1 = (x - bfh2f(h)) * 256.0f;
  m = btrunc(r1);
  float r2 = (r1 - bfh2f(m)) * 256.0f;
  l = btrunc(r2);
}
__device__ __forceinline__ float shrinkf(float c, float theta) {
  float a = fabsf(c) - theta;
  return (a > 0.0f) ? copysignf(a, c) : 0.0f;
}

// scalar conv (R6-proven): thread owns outputs [16t,16t+16), affine LDS base.
__device__ __forceinline__ void conv_row(const float* __restrict__ xw,
                                         const float* __restrict__ kn,
                                         float acc[16]) {
#pragma unroll
  for (int e = 0; e < 16; ++e) acc[e] = 0.0f;
#pragma unroll
  for (int m = 0; m < 79; ++m) {
    float wv = xw[WOFF(1 + m)];
    const int jlo = (m - 15 > 0) ? (m - 15) : 0;
    const int jhi = (m < 63) ? m : 63;
#pragma unroll
    for (int j = jlo; j <= jhi; ++j) acc[m - j] = fmaf(kn[j], wv, acc[m - j]);
  }
}

// One block = one row; wave w owns outputs [1024w,1024w+1024) as 4 tiles T.
// D[e][p] = sum_q Kmat[e][q] * x[16p-32+q], q in [0,96); Kmat = I - K/L.
__global__ __launch_bounds__(256, 3) void ista_mfma(
    const float* __restrict__ y, const float* __restrict__ pulse,
    float* __restrict__ xout) {
  __shared__ __align__(16) char pool[POOLB];
  __shared__ float pl[KW];
  __shared__ float knl[KW];

  const int t = threadIdx.x, w = t >> 6, l = t & 63, lc = l & 15, kb = l >> 4;
  const int row = blockIdx.x;

  if (t < KW) pl[t] = pulse[t];

  // zero buf0 halos (3 level arrays)
#pragma unroll
  for (int a = 0; a < 3; ++a) {
    char* ab = pool + a * AS;
    if (t < 16) *(unsigned*)(ab + 4 * t) = 0u;
    if (t < 24) *(unsigned*)(ab + 8256 + 4 * t) = 0u;
  }

  // stage y as f32 (PADW layout) into the buf1 region
  float* yw = (float*)(pool + SLOT);
  if (t < HALO) { yw[PADW(t)] = 0.0f; yw[PADW(NLOG - HALO + t)] = 0.0f; }
  const float* yrow = y + (size_t)row * LROW;
#pragma unroll
  for (int q = 0; q < 4; ++q) {
    int i4 = q * 256 + t; float4 v = ((const float4*)yrow)[i4];
    yw[PADW(HALO + 4 * i4 + 0)] = v.x; yw[PADW(HALO + 4 * i4 + 1)] = v.y;
    yw[PADW(HALO + 4 * i4 + 2)] = v.z; yw[PADW(HALO + 4 * i4 + 3)] = v.w;
  }
  __syncthreads();                       // (A) pl, y staged

  float Lc = 0.0f;
#pragma unroll
  for (int j = 0; j < KW; ++j) Lc += pl[j] * pl[j];
  const float theta = 0.1f / Lc, invL = 1.0f / Lc;
  if (t < KW) knl[t] = pl[KW - 1 - t] / Lc;

  // scaled operator frags (A operand) for Bc = I - K/L
  short8 Ah[3], Am[3], Al[3];
#pragma unroll
  for (int kf = 0; kf < 3; ++kf) {
#pragma unroll
    for (int j = 0; j < 8; ++j) {
      int q = 32 * kf + 8 * kb + j, d = q - lc - 1;
      float v = (d >= 0 && d < 64) ? pl[63 - d] * invL : 0.0f;
      float vc = ((q == lc + 32) ? 1.0f : 0.0f) - v;
      unsigned short h, m, lo; split3s(vc, h, m, lo);
      Ah[kf][j] = (short)h; Am[kf][j] = (short)m; Al[kf][j] = (short)lo;
    }
  }
  __syncthreads();                       // (B) knl visible

  // exact f32 B_term via scalar conv (one-time), thread-t element layout
  float bts[16];
  conv_row(yw + 17 * t, knl, bts);
  __syncthreads();                       // (C) all y reads done

  // re-layout bt: write f32 over the (dead) y region, read back in C-layout
#pragma unroll
  for (int e = 0; e < 16; ++e) (yw + 17 * t)[WOFF(32 + e)] = bts[e];
  __syncthreads();                       // (D)

  f32x4 bt[4];
#pragma unroll
  for (int T = 0; T < 4; ++T) {
    const int n0 = 1024 * w + 256 * T + 16 * lc + 4 * kb;
#pragma unroll
    for (int i = 0; i < 4; ++i) bt[T][i] = yw[PADW(HALO + n0 + i)];
  }
  __syncthreads();                       // (E) bt reads done; buf1 now free

  // zero buf1 halos; x1 = shrink(bt) -> buf1 (scaled bf16x3, C-layout)
#pragma unroll
  for (int a = 0; a < 3; ++a) {
    char* ab = pool + SLOT + a * AS;
    if (t < 16) *(unsigned*)(ab + 4 * t) = 0u;
    if (t < 24) *(unsigned*)(ab + 8256 + 4 * t) = 0u;
  }
  const int rb_lane = 2048 * w + 32 * lc + 16 * kb;      // B-frag reads (b128)
  const int wb_lane = 2048 * w + 32 * lc + 8 * kb + 64;  // C writes (b64)
  {
    char* wp = pool + SLOT + wb_lane;
#pragma unroll
    for (int T = 0; T < 4; ++T) {
      short4v h4, m4, l4;
#pragma unroll
      for (int i = 0; i < 4; ++i) {
        float xn = shrinkf(bt[T][i], theta);
        unsigned short h, m, lo; split3s(xn, h, m, lo);
        h4[i] = (short)h; m4[i] = (short)m; l4[i] = (short)lo;
      }
      *(short4v*)(wp + 512 * T)          = h4;
      *(short4v*)(wp + 512 * T + AS)     = m4;
      *(short4v*)(wp + 512 * T + 2 * AS) = l4;
    }
  }
  __syncthreads();                       // (F)

  constexpr float S8 = 1.0f / 256.0f, S16 = 1.0f / 65536.0f;

  // 19 iterations; three scale-grouped accumulators per tile
  for (int it = 0; it < 19; ++it) {
    const int rs = (it & 1) ? 0 : SLOT, ws = (it & 1) ? SLOT : 0;
    const char* rp = pool + rs + rb_lane;
    char* wp = pool + ws + wb_lane;
#pragma unroll
    for (int T = 0; T < 4; ++T) {
      f32x4 ah = bt[T], am = (f32x4)0.0f, al = (f32x4)0.0f;
#pragma unroll
      for (int kf = 0; kf < 3; ++kf) {
        const char* p = rp + 512 * T + 64 * kf;
        short8 xh = *(const short8*)(p);
        short8 xm = *(const short8*)(p + AS);
        short8 xl = *(const short8*)(p + 2 * AS);
        ah = __builtin_amdgcn_mfma_f32_16x16x32_bf16(Ah[kf], xh, ah, 0, 0, 0);
        am = __builtin_amdgcn_mfma_f32_16x16x32_bf16(Ah[kf], xm, am, 0, 0, 0);
        am = __builtin_amdgcn_mfma_f32_16x16x32_bf16(Am[kf], xh, am, 0, 0, 0);
        al = __builtin_amdgcn_mfma_f32_16x16x32_bf16(Ah[kf], xl, al, 0, 0, 0);
        al = __builtin_amdgcn_mfma_f32_16x16x32_bf16(Am[kf], xm, al, 0, 0, 0);
        al = __builtin_amdgcn_mfma_f32_16x16x32_bf16(Al[kf], xh, al, 0, 0, 0);
      }
      short4v h4, m4, l4;
#pragma unroll
      for (int i = 0; i < 4; ++i) {
        float c  = fmaf(S16, al[i], fmaf(S8, am[i], ah[i]));
        float xn = shrinkf(c, theta);
        unsigned short h, m, lo; split3s(xn, h, m, lo);
        h4[i] = (short)h; m4[i] = (short)m; l4[i] = (short)lo;
      }
      *(short4v*)(wp + 512 * T)          = h4;
      *(short4v*)(wp + 512 * T + AS)     = m4;
      *(short4v*)(wp + 512 * T + 2 * AS) = l4;
    }
    __syncthreads();
  }

  // final x in buf0: x = h + S8*m + S16*l; coalesced float4 write
  {
    const char* hp = pool + 64 + 32 * t;
    float o[16];
#pragma unroll
    for (int s = 0; s < 2; ++s) {
      short8 hv = *(const short8*)(hp + 16 * s);
      short8 mv = *(const short8*)(hp + AS + 16 * s);
      short8 lv = *(const short8*)(hp + 2 * AS + 16 * s);
#pragma unroll
      for (int c2 = 0; c2 < 8; ++c2) {
        float xv = fmaf(S8, bfh2f((unsigned short)mv[c2]),
                        bfh2f((unsigned short)hv[c2]));
        o[8 * s + c2] = fmaf(S16, bfh2f((unsigned short)lv[c2]), xv);
      }
    }
    float4* xr = (float4*)(xout + (size_t)row * LROW + 16 * t);
#pragma unroll
    for (int s = 0; s < 4; ++s)
      xr[s] = make_float4(o[4 * s], o[4 * s + 1], o[4 * s + 2], o[4 * s + 3]);
  }
}

// ---------------- MLP via bf16 MFMA (validated in R2) ----------------
__device__ __forceinline__ unsigned short f2bf(float f) {
  unsigned u = __float_as_uint(f);
  u += 0x7fffu + ((u >> 16) & 1u);      // RNE
  return (unsigned short)(u >> 16);
}

__global__ __launch_bounds__(256) void cast_w1(const float* __restrict__ W1,
                                               unsigned short* __restrict__ W1p) {
  const int kq = blockIdx.x;
  const int c  = threadIdx.x;
  short8 v;
#pragma unroll
  for (int j = 0; j < 8; ++j)
    v[j] = (short)f2bf(W1[(size_t)(kq * 8 + j) * 256 + c]);
  *(short8*)(W1p + ((size_t)kq * 256 + c) * 8) = v;
}

__global__ __launch_bounds__(256) void mlp_mfma(
    const float* __restrict__ x, const unsigned short* __restrict__ W1p,
    const float* __restrict__ b1, const float* __restrict__ W2,
    const float* __restrict__ b2, float* __restrict__ out1) {
  __shared__ short Ap[16 * 8 * 8];
  __shared__ short Bp[8 * 256 * 8];
  __shared__ float pr[4][16];

  const int t = threadIdx.x;
  const int w = t >> 6;
  const int l = t & 63;
  const int lrow = l & 15;
  const int lk   = l >> 4;
  const int row0 = blockIdx.x * 16;

  f32x4 acc[4];
#pragma unroll
  for (int n = 0; n < 4; ++n) acc[n] = (f32x4)0.0f;

  for (int kt = 0; kt < 64; ++kt) {
    __syncthreads();
    {
      const int r  = t >> 4;
      const int k4 = t & 15;
      const float4 v = *(const float4*)(x + (size_t)(row0 + r) * LROW + kt * 64 + k4 * 4);
      short4v a;
      a.x = (short)f2bf(v.x); a.y = (short)f2bf(v.y);
      a.z = (short)f2bf(v.z); a.w = (short)f2bf(v.w);
      const int kq = k4 >> 1, h = k4 & 1;
      *(short4v*)((char*)Ap + ((r * 8 + (kq ^ (r & 7))) * 16 + h * 8)) = a;
    }
    {
      const short8* src = (const short8*)(W1p + (size_t)kt * (8 * 256 * 8));
      short8* dst = (short8*)Bp;
#pragma unroll
      for (int i = 0; i < 8; ++i) dst[t + 256 * i] = src[t + 256 * i];
    }
    __syncthreads();
#pragma unroll
    for (int kf = 0; kf < 2; ++kf) {
      const int kq = kf * 4 + lk;
      short8 af = *(short8*)((char*)Ap + (lrow * 8 + (kq ^ (lrow & 7))) * 16);
#pragma unroll
      for (int n = 0; n < 4; ++n) {
        short8 bf = *(short8*)((char*)Bp + (kq * 256 + w * 64 + n * 16 + lrow) * 16);
        acc[n] = __builtin_amdgcn_mfma_f32_16x16x32_bf16(af, bf, acc[n], 0, 0, 0);
      }
    }
  }

  float s[4] = {0.0f, 0.0f, 0.0f, 0.0f};
#pragma unroll
  for (int n = 0; n < 4; ++n) {
    const int c = w * 64 + n * 16 + lrow;
    const float b1v = b1[c];
    const float w2v = W2[c];
#pragma unroll
    for (int i = 0; i < 4; ++i) {
      float f = acc[n][i] + b1v;
      f = fmaxf(f, 0.0f);
      s[i] = fmaf(f, w2v, s[i]);
    }
  }
#pragma unroll
  for (int off = 1; off < 16; off <<= 1) {
#pragma unroll
    for (int i = 0; i < 4; ++i) s[i] += __shfl_xor(s[i], off, 64);
  }
  if (lrow == 0) {
#pragma unroll
    for (int i = 0; i < 4; ++i) pr[w][lk * 4 + i] = s[i];
  }
  __syncthreads();
  if (t < 16) {
    out1[row0 + t] =
        (pr[0][t] + pr[1][t] + pr[2][t] + pr[3][t] + b2[0]) * (float)LROW;
  }
}

extern "C" void kernel_launch(void* const* d_in, const int* in_sizes, int n_in,
                              void* d_out, int out_size, void* d_ws, size_t ws_size,
                              hipStream_t stream) {
  const float* y     = (const float*)d_in[0];
  const float* pulse = (const float*)d_in[1];
  const float* W1    = (const float*)d_in[2];
  const float* b1    = (const float*)d_in[3];
  const float* W2    = (const float*)d_in[4];
  const float* b2    = (const float*)d_in[5];

  float* xout = (float*)d_out;
  float* out1 = xout + (size_t)LROW * LROW;
  unsigned short* W1p = (unsigned short*)d_ws;

  cast_w1<<<512, 256, 0, stream>>>(W1, W1p);
  ista_mfma<<<LROW, 256, 0, stream>>>(y, pulse, xout);
  mlp_mfma<<<LROW / 16, 256, 0, stream>>>(xout, W1p, b1, W2, b2, out1);
}